// Round 18
// baseline (493.853 us; speedup 1.0000x reference)
//
#include <hip/hip_runtime.h>
#include <cstdint>

#define NB 32
#define IC 2048
#define IK 16
#define OC 64
#define OD 32
#define ODF (OC*OD)          // 2048 flattened od
#define PARTBLK16 (16*ODF)   // gemm0 slot: 16 local b (R16 format)
#define PARTBLK32 (32*ODF)   // saccum slot: all 32 b
#define NCH0 128             // gemm0 ci chunks (16 i, 2 twins -> grid 256)
#define NCHS 256             // agree/saccum ci chunks (8 i, grid 256)

typedef __fp16 h2 __attribute__((ext_vector_type(2)));
typedef __fp16 h8 __attribute__((ext_vector_type(8)));
typedef float  f4 __attribute__((ext_vector_type(4)));

__device__ __forceinline__ h2 pk2(float a, float b) {
#if __has_builtin(__builtin_amdgcn_cvt_pkrtz)
  return __builtin_amdgcn_cvt_pkrtz(a, b);
#else
  h2 r; r.x = (__fp16)a; r.y = (__fp16)b; return r;
#endif
}
__device__ __forceinline__ float fdot2a(h2 a, h2 b, float c) {
#if __has_builtin(__builtin_amdgcn_fdot2)
  return __builtin_amdgcn_fdot2(a, b, c, false);
#else
  return c + (float)a.x*(float)b.x + (float)a.y*(float)b.y;
#endif
}
__device__ __forceinline__ unsigned int bcu(h2 v){ return __builtin_bit_cast(unsigned int, v); }
__device__ __forceinline__ h2 bch2(unsigned int u){ return __builtin_bit_cast(h2, u); }
__device__ __forceinline__ h8 bch8(uint4 u){ return __builtin_bit_cast(h8, u); }
__device__ __forceinline__ f4 mfma_16x16x32(h8 a, h8 b, f4 c) {
  return __builtin_amdgcn_mfma_f32_16x16x32_f16(a, b, c, 0, 0, 0);
}
__device__ __forceinline__ uint4 packw(const float* wp) {
  const float4 wa = *(const float4*)wp;
  const float4 wb = *(const float4*)(wp + 4);
  uint4 au;
  au.x = bcu(pk2(wa.x, wa.y)); au.y = bcu(pk2(wa.z, wa.w));
  au.z = bcu(pk2(wb.x, wb.y)); au.w = bcu(pk2(wb.z, wb.w));
  return au;
}

// R17 lesson: saccum wg-count + unroll were NOT the limit; the 2x W stream
// (one per bh twin) was. R18: agree/saccum cover ALL 32 b per wg (two
// b-halves share every loaded W fragment -> W read ONCE per kernel).
// gemm0 + its reduce unchanged (at roofline).

// K0: iter-1 GEMM (c=1/64 exact), two i per MFMA, bh twins (R16-verified).
template<int WH>
__global__ __launch_bounds__(1024)
void caps_gemm0(const float* __restrict__ xg, const float* __restrict__ Wg,
                uint4* __restrict__ Whg, float* __restrict__ part)
{
  __shared__ uint4 x_h[8][2][16];
  const int t = threadIdx.x, w = t >> 6, l = t & 63, lb = l & 15, lg = l >> 4;
  const int bid = blockIdx.x, slot = bid >> 3;
  const int bh = slot & 1;
  const int ci = (bid & 7)*16 + (slot >> 1);     // XCD-grouped twins
  const int i0 = ci*16, bg0 = bh*16;
  const f4 zf = {0.f,0.f,0.f,0.f};
  f4 acc[8];
#pragma unroll
  for (int q = 0; q < 8; ++q) acc[q] = zf;

  for (int g8 = 0; g8 < 16; g8 += 8) {
    if (g8) __syncthreads();
    if (t < 256) {
      const int si = t >> 5, kc2 = (t >> 4) & 1, sb = t & 15;
      const float* xp = &xg[((size_t)(bg0 + sb)*IC + (i0 + g8 + si))*IK + kc2*8];
      x_h[si][kc2][sb] = packw(xp);
    }
    __syncthreads();
#pragma unroll 1
    for (int p = 0; p < 4; ++p) {
      const int isel = lg >> 1, kc = lg & 1, il = p*2 + isel;
      const h8 B = bch8(x_h[il][kc][lb]);
#pragma unroll
      for (int tt = 0; tt < 8; ++tt) {
        const size_t widx = (size_t)(i0 + g8 + il)*ODF + (w*8 + tt)*16 + lb;
        const uint4 au = packw(&Wg[widx*IK + kc*8]);
        if (WH && bh == 0) Whg[widx*2 + kc] = au;
        acc[tt] = mfma_16x16x32(bch8(au), B, acc[tt]);
      }
    }
  }
  float* pp = part + (size_t)(ci*2 + bh)*PARTBLK16;
#pragma unroll
  for (int tt = 0; tt < 8; ++tt) {
    float4 st;
    st.x = acc[tt].x*(1.f/64.f); st.y = acc[tt].y*(1.f/64.f);
    st.z = acc[tt].z*(1.f/64.f); st.w = acc[tt].w*(1.f/64.f);
    *(float4*)&pp[(size_t)lb*ODF + (w*8 + tt)*16 + lg*4] = st;
  }
}

// KA v2: agreement + softmax + c write; ALL 32 b per wg, W read once.
// grid 256 (8-i chunks), 16 waves, 3 barriers. Sum/diff dense i-pairs,
// each A-load feeds both b-halves (2x MFMA per load).
template<int ITER, int WH>
__global__ __launch_bounds__(1024)
void caps_agree(const float* __restrict__ xg, const float* __restrict__ Wg,
                const uint4* __restrict__ Whg, const float* __restrict__ vin,
                float* __restrict__ a1g, float* __restrict__ cg)
{
  __shared__ uint4 x_h[8][2][32];                // 16 KB
  __shared__ float agr[8*64*33];                 // 67.6 KB [ii][o][b33]
  const int t = threadIdx.x, w = t >> 6, l = t & 63, lb = l & 15, lg = l >> 4;
  const int i0 = blockIdx.x * 8;                 // grid 256
  const f4 zf = {0.f,0.f,0.f,0.f};

  if (t < 512) {
    const int si = t >> 6, kc2 = (t >> 5) & 1, sb = t & 31;
    x_h[si][kc2][sb] = packw(&xg[((size_t)sb*IC + (i0 + si))*IK + kc2*8]);
  }
  unsigned int vh[2][16];                        // v*0.5 f16, both b-halves
#pragma unroll
  for (int b2 = 0; b2 < 2; ++b2)
#pragma unroll
    for (int tt = 0; tt < 8; ++tt) {
      const int o = w*4 + (tt >> 1);
      const float4 vv = *(const float4*)
        &vin[((size_t)(b2*16 + lb)*OC + o)*OD + (tt & 1)*16 + lg*4];
      vh[b2][tt*2]   = bcu(pk2(0.5f*vv.x, 0.5f*vv.y));
      vh[b2][tt*2+1] = bcu(pk2(0.5f*vv.z, 0.5f*vv.w));
    }
  __syncthreads();

  const int isel = lg >> 1, kc = lg & 1;
  const unsigned int msk = (lg >= 2) ? 0x80008000u : 0u;

#pragma unroll 1
  for (int p = 0; p < 4; ++p) {
    const int iA = i0 + p*2, iB = iA + 1;
    uint4 bu[2];
    bu[0] = x_h[p*2 + isel][kc][lb];
    bu[1] = x_h[p*2 + isel][kc][16 + lb];
    float ap1[2][4] = {{0.f,0.f,0.f,0.f},{0.f,0.f,0.f,0.f}};
    float ap2[2][4] = {{0.f,0.f,0.f,0.f},{0.f,0.f,0.f,0.f}};
#pragma unroll
    for (int tt = 0; tt < 8; ++tt) {
      const size_t widx = (size_t)(iA + isel)*ODF + (w*8 + tt)*16 + lb;
      const uint4 au = WH ? Whg[widx*2 + kc] : packw(&Wg[widx*IK + kc*8]);
      const h8 A = bch8(au);
#pragma unroll
      for (int b2 = 0; b2 < 2; ++b2) {
        const uint4 b0 = bu[b2];
        uint4 bm;
        bm.x = b0.x^msk; bm.y = b0.y^msk; bm.z = b0.z^msk; bm.w = b0.w^msk;
        const f4 s = mfma_16x16x32(A, bch8(b0), zf);   // uA + uB
        const f4 d = mfma_16x16x32(A, bch8(bm), zf);   // uA - uB
        const h2 sh0 = pk2(s.x, s.y), sh1 = pk2(s.z, s.w);
        const h2 dh0 = pk2(d.x, d.y), dh1 = pk2(d.z, d.w);
        const float ds = fdot2a(sh0, bch2(vh[b2][tt*2]),
                         fdot2a(sh1, bch2(vh[b2][tt*2+1]), 0.f));
        const float dd = fdot2a(dh0, bch2(vh[b2][tt*2]),
                         fdot2a(dh1, bch2(vh[b2][tt*2+1]), 0.f));
        ap1[b2][tt >> 1] += ds + dd;                   // uA . v
        ap2[b2][tt >> 1] += ds - dd;                   // uB . v
      }
    }
#pragma unroll
    for (int b2 = 0; b2 < 2; ++b2)
#pragma unroll
      for (int q = 0; q < 4; ++q) {
        float a1v = ap1[b2][q], a2v = ap2[b2][q];
        a1v += __shfl_xor(a1v, 16); a1v += __shfl_xor(a1v, 32);
        a2v += __shfl_xor(a2v, 16); a2v += __shfl_xor(a2v, 32);
        if (l < 16) {
          const int o = w*4 + q, b = b2*16 + lb;
          float v1 = a1v, v2 = a2v;
          if (ITER == 2) {
            v1 += a1g[((size_t)iA*OC + o)*NB + b];
            v2 += a1g[((size_t)iB*OC + o)*NB + b];
          }
          if (ITER == 1) {
            a1g[((size_t)iA*OC + o)*NB + b] = v1;
            a1g[((size_t)iB*OC + o)*NB + b] = v2;
          }
          agr[((p*2)*64 + o)*33 + b]   = v1;
          agr[((p*2+1)*64 + o)*33 + b] = v2;
        }
      }
  }
  __syncthreads();
  // softmax: 256 (i,b) rows over o=0..63; 16 rows per wave; in-place c
#pragma unroll
  for (int r = 0; r < 16; ++r) {
    const int row = w*16 + r, si = row >> 5, b = row & 31;
    const float a = agr[(si*64 + l)*33 + b];     // o = l
    float m = a;
#pragma unroll
    for (int off = 1; off < 64; off <<= 1) m = fmaxf(m, __shfl_xor(m, off));
    const float e = __expf(a - m);
    float se = e;
#pragma unroll
    for (int off = 1; off < 64; off <<= 1) se += __shfl_xor(se, off);
    agr[(si*64 + l)*33 + b] = e / se;
  }
  __syncthreads();
  // coalesced c flush: [i][o][b32]
#pragma unroll
  for (int cc = 0; cc < 8; ++cc)
#pragma unroll
    for (int r = 0; r < 2; ++r) {
      const int idx = r*1024 + t, o = idx >> 5, b = idx & 31;
      cg[((size_t)(i0 + cc)*OC + o)*NB + b] = agr[(cc*64 + o)*33 + b];
    }
}

// KB v2: s accumulation; ALL 32 b per wg, each A-load feeds 2 MFMAs.
// c folded into B. grid 256 (8-i chunks), 1 barrier, acc[16] f4.
template<int WH>
__global__ __launch_bounds__(1024)
void caps_saccum(const float* __restrict__ xg, const float* __restrict__ Wg,
                 const uint4* __restrict__ Whg, const float* __restrict__ cg,
                 float* __restrict__ part)
{
  __shared__ uint4 x_h[8][2][32];
  const int t = threadIdx.x, w = t >> 6, l = t & 63, lb = l & 15, lg = l >> 4;
  const int ci = blockIdx.x;                     // 0..255
  const int i0 = ci*8;
  const f4 zf = {0.f,0.f,0.f,0.f};
  f4 acc[16];                                    // [tt][b-half]
#pragma unroll
  for (int q = 0; q < 16; ++q) acc[q] = zf;
  const int isel = lg >> 1, kc = lg & 1;

  if (t < 512) {
    const int si = t >> 6, kc2 = (t >> 5) & 1, sb = t & 31;
    x_h[si][kc2][sb] = packw(&xg[((size_t)sb*IC + (i0 + si))*IK + kc2*8]);
  }
  __syncthreads();

#pragma unroll 1
  for (int p = 0; p < 4; ++p) {
    const int iA = i0 + p*2, iB = iA + 1;
    uint4 bu[2];
    bu[0] = x_h[p*2 + isel][kc][lb];
    bu[1] = x_h[p*2 + isel][kc][16 + lb];
#pragma unroll
    for (int q = 0; q < 4; ++q) {                // o = w*4 + q
      const int o = w*4 + q;
      h8 Bs[2];
#pragma unroll
      for (int b2 = 0; b2 < 2; ++b2) {
        const int b = b2*16 + lb;
        const float c1 = cg[((size_t)iA*OC + o)*NB + b];
        const float c2 = cg[((size_t)iB*OC + o)*NB + b];
        const float cs = (lg < 2) ? c1 : c2;     // my K-half's i
        const h2 cpk = pk2(cs, cs);
        uint4 bs;
        bs.x = bcu(bch2(bu[b2].x)*cpk); bs.y = bcu(bch2(bu[b2].y)*cpk);
        bs.z = bcu(bch2(bu[b2].z)*cpk); bs.w = bcu(bch2(bu[b2].w)*cpk);
        Bs[b2] = bch8(bs);
      }
#pragma unroll
      for (int th = 0; th < 2; ++th) {
        const int tt = q*2 + th;
        const size_t widx = (size_t)(iA + isel)*ODF + (w*8 + tt)*16 + lb;
        const uint4 au = WH ? Whg[widx*2 + kc] : packw(&Wg[widx*IK + kc*8]);
        const h8 A = bch8(au);
        acc[tt*2]   = mfma_16x16x32(A, Bs[0], acc[tt*2]);
        acc[tt*2+1] = mfma_16x16x32(A, Bs[1], acc[tt*2+1]);
      }
    }
  }
  float* pp = part + (size_t)ci*PARTBLK32;
#pragma unroll
  for (int tt = 0; tt < 8; ++tt)
#pragma unroll
    for (int b2 = 0; b2 < 2; ++b2) {
      const f4 a = acc[tt*2 + b2];
      float4 st; st.x = a.x; st.y = a.y; st.z = a.z; st.w = a.w;
      *(float4*)&pp[(size_t)(b2*16 + lb)*ODF + (w*8 + tt)*16 + lg*4] = st;
    }
}

// reduce MODE 0: gemm0 format (bh twins, 16-b slots, nci=128 pairs).
// reduce MODE 1: saccum format (32-b slots, 256 linear slots).
template<int MODE>
__global__ __launch_bounds__(64)
void caps_reduce(const float* __restrict__ part, float* __restrict__ vout)
{
  const int r  = blockIdx.x;           // b*OC + o
  const int b  = r >> 6, o = r & 63;
  const int d  = threadIdx.x & 31;
  const int h  = threadIdx.x >> 5;
  float s = 0.f;
  if (MODE == 0) {
    const int bh = b >> 4, bl = b & 15;
    const float* p = part + (size_t)bh*PARTBLK16 + (size_t)bl*ODF + o*OD + d;
#pragma unroll 4
    for (int q = 0; q < 64; ++q)
      s += p[(size_t)((h*64 + q)*2)*PARTBLK16];
  } else {
    const float* p = part + (size_t)b*ODF + o*OD + d;
#pragma unroll 4
    for (int q = 0; q < 128; ++q)
      s += p[(size_t)(h*128 + q)*PARTBLK32];
  }
  s += __shfl_xor(s, 32);
  float n2 = s*s;
#pragma unroll
  for (int off = 1; off < 32; off <<= 1) n2 += __shfl_xor(n2, off);
  const float n = sqrtf(n2);
  const float f = n2 / ((1.f + n2)*(n + 1e-8f));
  if (h == 0) vout[(size_t)r*OD + d] = s*f;
}

extern "C" void kernel_launch(void* const* d_in, const int* in_sizes, int n_in,
                              void* d_out, int out_size, void* d_ws, size_t ws_size,
                              hipStream_t stream)
{
  const float* xg = (const float*)d_in[0];
  const float* Wg = (const float*)d_in[1];
  float* out = (float*)d_out;

  const size_t part_b = (size_t)NCHS*PARTBLK32*sizeof(float);  // 64 MB
  const size_t a1_b   = (size_t)IC*OC*NB*sizeof(float);        // 16 MB
  const size_t c_b    = a1_b;                                  // 16 MB
  const size_t v_b    = (size_t)NB*ODF*sizeof(float);          // 256 KB
  const size_t wh_b   = (size_t)IC*ODF*IK*2;                   // 128 MB f16 W

  char* ws = (char*)d_ws;
  float* part = (float*)ws;                  ws += part_b;
  float* a1g  = (float*)ws;                  ws += a1_b;
  float* cg   = (float*)ws;                  ws += c_b;
  float* vbuf = (float*)ws;                  ws += v_b;
  uint4* whg  = (uint4*)ws;
  const bool WH = (part_b + a1_b + c_b + v_b + wh_b) <= ws_size;

  if (WH) {
    caps_gemm0<1><<<NCH0*2, 1024, 0, stream>>>(xg, Wg, whg, part);
    caps_reduce<0><<<NB*OC, 64, 0, stream>>>(part, vbuf);
    caps_agree<1,1><<<NCHS, 1024, 0, stream>>>(xg, Wg, whg, vbuf, a1g, cg);
    caps_saccum<1><<<NCHS, 1024, 0, stream>>>(xg, Wg, whg, cg, part);
    caps_reduce<1><<<NB*OC, 64, 0, stream>>>(part, vbuf);
    caps_agree<2,1><<<NCHS, 1024, 0, stream>>>(xg, Wg, whg, vbuf, a1g, cg);
    caps_saccum<1><<<NCHS, 1024, 0, stream>>>(xg, Wg, whg, cg, part);
    caps_reduce<1><<<NB*OC, 64, 0, stream>>>(part, out);
  } else {
    caps_gemm0<0><<<NCH0*2, 1024, 0, stream>>>(xg, Wg, nullptr, part);
    caps_reduce<0><<<NB*OC, 64, 0, stream>>>(part, vbuf);
    caps_agree<1,0><<<NCHS, 1024, 0, stream>>>(xg, Wg, nullptr, vbuf, a1g, cg);
    caps_saccum<0><<<NCHS, 1024, 0, stream>>>(xg, Wg, nullptr, cg, part);
    caps_reduce<1><<<NB*OC, 64, 0, stream>>>(part, vbuf);
    caps_agree<2,0><<<NCHS, 1024, 0, stream>>>(xg, Wg, nullptr, vbuf, a1g, cg);
    caps_saccum<0><<<NCHS, 1024, 0, stream>>>(xg, Wg, nullptr, cg, part);
    caps_reduce<1><<<NB*OC, 64, 0, stream>>>(part, out);
  }
}

// Round 19
// 290.903 us; speedup vs baseline: 1.6977x; 1.6977x over previous
//
#include <hip/hip_runtime.h>
#include <cstdint>

#define NB 32
#define IC 2048
#define IK 16
#define OC 64
#define OD 32
#define ODF (OC*OD)          // 2048 flattened od
#define PARTBLK16 (16*ODF)   // gemm0 slot: 16 local b (R16 format)
#define PARTBLK32 (32*ODF)   // saccum slot: all 32 b (65536 floats)
#define NCH0 128             // gemm0 ci chunks (16 i, 2 twins -> grid 256)
#define NCHA 256             // agree ci chunks (8 i, bh twins -> grid 512)
#define NCHS 128             // saccum ci chunks (16 i, 4 od-quarters -> grid 512)

typedef __fp16 h2 __attribute__((ext_vector_type(2)));
typedef __fp16 h8 __attribute__((ext_vector_type(8)));
typedef float  f4 __attribute__((ext_vector_type(4)));

__device__ __forceinline__ h2 pk2(float a, float b) {
#if __has_builtin(__builtin_amdgcn_cvt_pkrtz)
  return __builtin_amdgcn_cvt_pkrtz(a, b);
#else
  h2 r; r.x = (__fp16)a; r.y = (__fp16)b; return r;
#endif
}
__device__ __forceinline__ float fdot2a(h2 a, h2 b, float c) {
#if __has_builtin(__builtin_amdgcn_fdot2)
  return __builtin_amdgcn_fdot2(a, b, c, false);
#else
  return c + (float)a.x*(float)b.x + (float)a.y*(float)b.y;
#endif
}
__device__ __forceinline__ unsigned int bcu(h2 v){ return __builtin_bit_cast(unsigned int, v); }
__device__ __forceinline__ h2 bch2(unsigned int u){ return __builtin_bit_cast(h2, u); }
__device__ __forceinline__ h8 bch8(uint4 u){ return __builtin_bit_cast(h8, u); }
__device__ __forceinline__ f4 mfma_16x16x32(h8 a, h8 b, f4 c) {
  return __builtin_amdgcn_mfma_f32_16x16x32_f16(a, b, c, 0, 0, 0);
}
__device__ __forceinline__ uint4 packw(const float* wp) {
  const float4 wa = *(const float4*)wp;
  const float4 wb = *(const float4*)(wp + 4);
  uint4 au;
  au.x = bcu(pk2(wa.x, wa.y)); au.y = bcu(pk2(wa.z, wa.w));
  au.z = bcu(pk2(wb.x, wb.y)); au.w = bcu(pk2(wb.z, wb.w));
  return au;
}

// R18 lesson: all-32-b per wg at 1024 thr blows the 64-VGPR cap (acc[16]=64
// regs alone) -> spill -> 494us. R19: revert gemm0/agree/reduce to R16's
// proven forms; rebuild ONLY saccum with an od-QUARTER split: 32 od-tiles
// per wg (2/wave), all 32 b, acc[2][2]=16 regs. W partitioned over quarters
// -> Whg read ONCE chip-wide (was 2x). 16-i chunks keep part at 32 MB.

// K0: iter-1 GEMM (c=1/64 exact), two i per MFMA, bh twins (R16-verified).
template<int WH>
__global__ __launch_bounds__(1024)
void caps_gemm0(const float* __restrict__ xg, const float* __restrict__ Wg,
                uint4* __restrict__ Whg, float* __restrict__ part)
{
  __shared__ uint4 x_h[8][2][16];
  const int t = threadIdx.x, w = t >> 6, l = t & 63, lb = l & 15, lg = l >> 4;
  const int bid = blockIdx.x, slot = bid >> 3;
  const int bh = slot & 1;
  const int ci = (bid & 7)*16 + (slot >> 1);     // XCD-grouped twins
  const int i0 = ci*16, bg0 = bh*16;
  const f4 zf = {0.f,0.f,0.f,0.f};
  f4 acc[8];
#pragma unroll
  for (int q = 0; q < 8; ++q) acc[q] = zf;

  for (int g8 = 0; g8 < 16; g8 += 8) {
    if (g8) __syncthreads();
    if (t < 256) {
      const int si = t >> 5, kc2 = (t >> 4) & 1, sb = t & 15;
      const float* xp = &xg[((size_t)(bg0 + sb)*IC + (i0 + g8 + si))*IK + kc2*8];
      x_h[si][kc2][sb] = packw(xp);
    }
    __syncthreads();
#pragma unroll 1
    for (int p = 0; p < 4; ++p) {
      const int isel = lg >> 1, kc = lg & 1, il = p*2 + isel;
      const h8 B = bch8(x_h[il][kc][lb]);
#pragma unroll
      for (int tt = 0; tt < 8; ++tt) {
        const size_t widx = (size_t)(i0 + g8 + il)*ODF + (w*8 + tt)*16 + lb;
        const uint4 au = packw(&Wg[widx*IK + kc*8]);
        if (WH && bh == 0) Whg[widx*2 + kc] = au;
        acc[tt] = mfma_16x16x32(bch8(au), B, acc[tt]);
      }
    }
  }
  float* pp = part + (size_t)(ci*2 + bh)*PARTBLK16;
#pragma unroll
  for (int tt = 0; tt < 8; ++tt) {
    float4 st;
    st.x = acc[tt].x*(1.f/64.f); st.y = acc[tt].y*(1.f/64.f);
    st.z = acc[tt].z*(1.f/64.f); st.w = acc[tt].w*(1.f/64.f);
    *(float4*)&pp[(size_t)lb*ODF + (w*8 + tt)*16 + lg*4] = st;
  }
}

// KA: agreement + softmax + coalesced c write (exact R16 form, proven 50us).
template<int ITER, int WH>
__global__ __launch_bounds__(1024)
void caps_agree(const float* __restrict__ xg, const float* __restrict__ Wg,
                const uint4* __restrict__ Whg, const float* __restrict__ vin,
                float* __restrict__ a1g, float* __restrict__ cg)
{
  __shared__ uint4 x_h[8][2][16];
  __shared__ float agr[8*64*17];                 // 34.8 KB [ii][o][b]
  const int t = threadIdx.x, w = t >> 6, l = t & 63, lb = l & 15, lg = l >> 4;
  const int bid = blockIdx.x, slot = bid >> 3;
  const int bh = slot & 1;
  const int ci8 = (bid & 7)*32 + (slot >> 1);    // 0..255
  const int i0 = ci8*8, bg0 = bh*16;
  const f4 zf = {0.f,0.f,0.f,0.f};

  if (t < 256) {
    const int si = t >> 5, kc2 = (t >> 4) & 1, sb = t & 15;
    const float* xp = &xg[((size_t)(bg0 + sb)*IC + (i0 + si))*IK + kc2*8];
    x_h[si][kc2][sb] = packw(xp);
  }
  unsigned int vh[16];
#pragma unroll
  for (int tt = 0; tt < 8; ++tt) {
    const int o = w*4 + (tt >> 1);
    const float4 vv = *(const float4*)
      &vin[((size_t)(bg0 + lb)*OC + o)*OD + (tt & 1)*16 + lg*4];
    vh[tt*2]   = bcu(pk2(0.5f*vv.x, 0.5f*vv.y));
    vh[tt*2+1] = bcu(pk2(0.5f*vv.z, 0.5f*vv.w));
  }
  __syncthreads();

  const int isel = lg >> 1, kc = lg & 1;
  const unsigned int msk = (lg >= 2) ? 0x80008000u : 0u;   // negate i2 K-half

#pragma unroll 1
  for (int p = 0; p < 4; ++p) {                  // i-pair
    const int iA = i0 + p*2, iB = iA + 1;
    const uint4 bu = x_h[p*2 + isel][kc][lb];
    uint4 bm;
    bm.x = bu.x^msk; bm.y = bu.y^msk; bm.z = bu.z^msk; bm.w = bu.w^msk;
    const h8 Bp = bch8(bu), Bm = bch8(bm);
    float ap1[4] = {0.f,0.f,0.f,0.f}, ap2[4] = {0.f,0.f,0.f,0.f};
#pragma unroll
    for (int tt = 0; tt < 8; ++tt) {
      const size_t widx = (size_t)(iA + isel)*ODF + (w*8 + tt)*16 + lb;
      const uint4 au = WH ? Whg[widx*2 + kc] : packw(&Wg[widx*IK + kc*8]);
      const h8 A = bch8(au);
      const f4 s = mfma_16x16x32(A, Bp, zf);     // u_iA + u_iB
      const f4 d = mfma_16x16x32(A, Bm, zf);     // u_iA - u_iB
      const h2 sh0 = pk2(s.x, s.y), sh1 = pk2(s.z, s.w);
      const h2 dh0 = pk2(d.x, d.y), dh1 = pk2(d.z, d.w);
      const float ds = fdot2a(sh0, bch2(vh[tt*2]), fdot2a(sh1, bch2(vh[tt*2+1]), 0.f));
      const float dd = fdot2a(dh0, bch2(vh[tt*2]), fdot2a(dh1, bch2(vh[tt*2+1]), 0.f));
      ap1[tt >> 1] += ds + dd;                   // u_iA . v
      ap2[tt >> 1] += ds - dd;                   // u_iB . v
    }
#pragma unroll
    for (int q = 0; q < 4; ++q) {
      float a1v = ap1[q], a2v = ap2[q];
      a1v += __shfl_xor(a1v, 16); a1v += __shfl_xor(a1v, 32);
      a2v += __shfl_xor(a2v, 16); a2v += __shfl_xor(a2v, 32);
      if (l < 16) {
        const int o = w*4 + q;
        float b1 = a1v, b2 = a2v;
        if (ITER == 2) {
          b1 += a1g[((size_t)iA*OC + o)*NB + bg0 + lb];
          b2 += a1g[((size_t)iB*OC + o)*NB + bg0 + lb];
        }
        if (ITER == 1) {
          a1g[((size_t)iA*OC + o)*NB + bg0 + lb] = b1;
          a1g[((size_t)iB*OC + o)*NB + bg0 + lb] = b2;
        }
        agr[((p*2)*64 + o)*17 + lb]   = b1;
        agr[((p*2+1)*64 + o)*17 + lb] = b2;
      }
    }
  }
  __syncthreads();
#pragma unroll
  for (int r = 0; r < 8; ++r) {
    const int row = w*8 + r, si = row >> 4, b = row & 15;
    const float a = agr[(si*64 + l)*17 + b];     // o = l
    float m = a;
#pragma unroll
    for (int off = 1; off < 64; off <<= 1) m = fmaxf(m, __shfl_xor(m, off));
    const float e = __expf(a - m);
    float se = e;
#pragma unroll
    for (int off = 1; off < 64; off <<= 1) se += __shfl_xor(se, off);
    agr[(si*64 + l)*17 + b] = e / se;
  }
  __syncthreads();
#pragma unroll
  for (int cc = 0; cc < 8; ++cc) {
    const int o = t >> 4, b2 = t & 15;
    cg[((size_t)(i0 + cc)*OC + o)*NB + bg0 + b2] = agr[(cc*64 + o)*17 + b2];
  }
}

// KB v3: s accumulation, od-QUARTER split. wg = (ci of 16 i, oq of 32 tiles).
// All 32 b; wave w covers tiles oq*32 + w*2 + tt (tt=0..1); acc[2][2]=16 regs.
// Whg read once chip-wide. grid 512, 2 wg/CU, 32 waves/CU.
template<int WH>
__global__ __launch_bounds__(1024)
void caps_saccum(const float* __restrict__ xg, const float* __restrict__ Wg,
                 const uint4* __restrict__ Whg, const float* __restrict__ cg,
                 float* __restrict__ part)
{
  __shared__ uint4 x_h[8][2][32];                // 8 KB
  const int t = threadIdx.x, w = t >> 6, l = t & 63, lb = l & 15, lg = l >> 4;
  const int ci = blockIdx.x >> 2;                // 0..127 (16-i chunks)
  const int oq = blockIdx.x & 3;                 // od-quarter
  const int i0 = ci*16;
  const f4 zf = {0.f,0.f,0.f,0.f};
  f4 acc[2][2];                                  // [tt][b2]
  acc[0][0] = zf; acc[0][1] = zf; acc[1][0] = zf; acc[1][1] = zf;
  const int isel = lg >> 1, kc = lg & 1;
  const int tile0 = oq*32 + w*2;                 // this wave's first tile

  for (int g8 = 0; g8 < 16; g8 += 8) {
    if (g8) __syncthreads();
    if (t < 512) {                               // stage x[32 b][8 i][16 k]
      const int si = t >> 6, kc2 = (t >> 5) & 1, sb = t & 31;
      x_h[si][kc2][sb] = packw(&xg[((size_t)sb*IC + (i0 + g8 + si))*IK + kc2*8]);
    }
    __syncthreads();
#pragma unroll 1
    for (int p = 0; p < 4; ++p) {
      const int iA = i0 + g8 + p*2, iB = iA + 1;
      uint4 bu[2];
      bu[0] = x_h[p*2 + isel][kc][lb];
      bu[1] = x_h[p*2 + isel][kc][16 + lb];
#pragma unroll
      for (int tt = 0; tt < 2; ++tt) {
        const int tile = tile0 + tt;
        const int o = tile >> 1;
        const size_t widx = (size_t)(iA + isel)*ODF + tile*16 + lb;
        const uint4 au = WH ? Whg[widx*2 + kc] : packw(&Wg[widx*IK + kc*8]);
        const h8 A = bch8(au);
#pragma unroll
        for (int b2 = 0; b2 < 2; ++b2) {
          const int b = b2*16 + lb;
          const float c1 = cg[((size_t)iA*OC + o)*NB + b];
          const float c2 = cg[((size_t)iB*OC + o)*NB + b];
          const float cs = (lg < 2) ? c1 : c2;   // my K-half's i
          const h2 cpk = pk2(cs, cs);
          uint4 bs;
          bs.x = bcu(bch2(bu[b2].x)*cpk); bs.y = bcu(bch2(bu[b2].y)*cpk);
          bs.z = bcu(bch2(bu[b2].z)*cpk); bs.w = bcu(bch2(bu[b2].w)*cpk);
          acc[tt][b2] = mfma_16x16x32(A, bch8(bs), acc[tt][b2]);
        }
      }
    }
  }
  float* pp = part + (size_t)ci*PARTBLK32;
#pragma unroll
  for (int tt = 0; tt < 2; ++tt)
#pragma unroll
    for (int b2 = 0; b2 < 2; ++b2) {
      const f4 a = acc[tt][b2];
      float4 st; st.x = a.x; st.y = a.y; st.z = a.z; st.w = a.w;
      *(float4*)&pp[(size_t)(b2*16 + lb)*ODF + (tile0 + tt)*16 + lg*4] = st;
    }
}

// reduce MODE 0: gemm0 format (bh twins, 16-b slots, 128 ci pairs).
// reduce MODE 1: saccum format (32-b slots, 128 linear slots).
template<int MODE>
__global__ __launch_bounds__(64)
void caps_reduce(const float* __restrict__ part, float* __restrict__ vout)
{
  const int r  = blockIdx.x;           // b*OC + o
  const int b  = r >> 6, o = r & 63;
  const int d  = threadIdx.x & 31;
  const int h  = threadIdx.x >> 5;
  float s = 0.f;
  if (MODE == 0) {
    const int bh = b >> 4, bl = b & 15;
    const float* p = part + (size_t)bh*PARTBLK16 + (size_t)bl*ODF + o*OD + d;
#pragma unroll 4
    for (int q = 0; q < 64; ++q)
      s += p[(size_t)((h*64 + q)*2)*PARTBLK16];
  } else {
    const float* p = part + (size_t)b*ODF + o*OD + d;
#pragma unroll 4
    for (int q = 0; q < 64; ++q)
      s += p[(size_t)(h*64 + q)*PARTBLK32];
  }
  s += __shfl_xor(s, 32);
  float n2 = s*s;
#pragma unroll
  for (int off = 1; off < 32; off <<= 1) n2 += __shfl_xor(n2, off);
  const float n = sqrtf(n2);
  const float f = n2 / ((1.f + n2)*(n + 1e-8f));
  if (h == 0) vout[(size_t)r*OD + d] = s*f;
}

extern "C" void kernel_launch(void* const* d_in, const int* in_sizes, int n_in,
                              void* d_out, int out_size, void* d_ws, size_t ws_size,
                              hipStream_t stream)
{
  const float* xg = (const float*)d_in[0];
  const float* Wg = (const float*)d_in[1];
  float* out = (float*)d_out;

  const size_t part_b = (size_t)NCHS*PARTBLK32*sizeof(float);  // 32 MB
  const size_t a1_b   = (size_t)IC*OC*NB*sizeof(float);        // 16 MB
  const size_t c_b    = a1_b;                                  // 16 MB
  const size_t v_b    = (size_t)NB*ODF*sizeof(float);          // 256 KB
  const size_t wh_b   = (size_t)IC*ODF*IK*2;                   // 128 MB f16 W

  char* ws = (char*)d_ws;
  float* part = (float*)ws;                  ws += part_b;
  float* a1g  = (float*)ws;                  ws += a1_b;
  float* cg   = (float*)ws;                  ws += c_b;
  float* vbuf = (float*)ws;                  ws += v_b;
  uint4* whg  = (uint4*)ws;
  const bool WH = (part_b + a1_b + c_b + v_b + wh_b) <= ws_size;

  if (WH) {
    caps_gemm0<1><<<NCH0*2, 1024, 0, stream>>>(xg, Wg, whg, part);
    caps_reduce<0><<<NB*OC, 64, 0, stream>>>(part, vbuf);
    caps_agree<1,1><<<NCHA*2, 1024, 0, stream>>>(xg, Wg, whg, vbuf, a1g, cg);
    caps_saccum<1><<<NCHS*4, 1024, 0, stream>>>(xg, Wg, whg, cg, part);
    caps_reduce<1><<<NB*OC, 64, 0, stream>>>(part, vbuf);
    caps_agree<2,1><<<NCHA*2, 1024, 0, stream>>>(xg, Wg, whg, vbuf, a1g, cg);
    caps_saccum<1><<<NCHS*4, 1024, 0, stream>>>(xg, Wg, whg, cg, part);
    caps_reduce<1><<<NB*OC, 64, 0, stream>>>(part, out);
  } else {
    caps_gemm0<0><<<NCH0*2, 1024, 0, stream>>>(xg, Wg, nullptr, part);
    caps_reduce<0><<<NB*OC, 64, 0, stream>>>(part, vbuf);
    caps_agree<1,0><<<NCHA*2, 1024, 0, stream>>>(xg, Wg, nullptr, vbuf, a1g, cg);
    caps_saccum<0><<<NCHS*4, 1024, 0, stream>>>(xg, Wg, nullptr, cg, part);
    caps_reduce<1><<<NB*OC, 64, 0, stream>>>(part, vbuf);
    caps_agree<2,0><<<NCHA*2, 1024, 0, stream>>>(xg, Wg, nullptr, vbuf, a1g, cg);
    caps_saccum<0><<<NCHS*4, 1024, 0, stream>>>(xg, Wg, nullptr, cg, part);
    caps_reduce<1><<<NB*OC, 64, 0, stream>>>(part, out);
  }
}